// Round 7
// baseline (691.940 us; speedup 1.0000x reference)
//
#include <hip/hip_runtime.h>
#include <hip/hip_bf16.h>

#define TT 4096
#define NCH 32
#define BB 2

// All intermediates live in static device globals (not d_ws). Every element
// read is written earlier in the same launch.
__device__ float g_tok[(size_t)BB*TT*128];
__device__ float g_Qp [(size_t)BB*TT*128];
__device__ float g_Kp [(size_t)BB*TT*128];
__device__ float g_Vg [(size_t)BB*TT*128];
__device__ float g_numb[(size_t)BB*TT*128];
__device__ float g_Ssum[(size_t)BB*NCH*16384];
__device__ float g_Spre[(size_t)BB*NCH*16384];
__device__ float g_denb[(size_t)BB*TT];
__device__ float g_Sk [(size_t)BB*NCH*128];
__device__ float g_Skp[(size_t)BB*NCH*128];

__device__ __forceinline__ float phi_f(float x){ return x > 0.f ? x + 1.f : __expf(x); }
__device__ __forceinline__ float sigm_f(float x){ return 1.f/(1.f+__expf(-x)); }

// Build tokens: [xs, ys] rows + [query_x, 0] final row.
__global__ __launch_bounds__(256) void k0_build(const float* __restrict__ xs,
                                                const float* __restrict__ ys,
                                                const float* __restrict__ qx){
  long e = (long)blockIdx.x * 256 + threadIdx.x;   // total BB*TT*128 = 1048576
  int col = (int)(e & 127);
  long r = e >> 7;
  int t = (int)(r & (TT-1));
  int b = (int)(r >> 12);
  float v;
  if (t < TT-1) {
    v = (col < 127) ? xs[((long)b*(TT-1) + t)*127 + col] : ys[(long)b*(TT-1) + t];
  } else {
    v = (col < 127) ? qx[(long)b*127 + col] : 0.f;
  }
  g_tok[e] = v;
}

// LN1 + Q/K/V/G projections + phi/gating. 8 rows per block.
__global__ __launch_bounds__(256) void k1_ln_qkvg(
    const float* __restrict__ Wq, const float* __restrict__ Wk,
    const float* __restrict__ Wv, const float* __restrict__ Wg,
    const float* __restrict__ Wgb,
    const float* __restrict__ lnw, const float* __restrict__ lnb)
{
  __shared__ float xsl[8][128];
  int tid = threadIdx.x;
  long r0 = (long)blockIdx.x * 8;
  {
    int row = tid >> 5;
    int col = (tid & 31) << 2;
    float4 v = *(const float4*)(g_tok + (r0 + row)*128 + col);
    float s1 = v.x+v.y+v.z+v.w;
    float s2 = v.x*v.x+v.y*v.y+v.z*v.z+v.w*v.w;
    #pragma unroll
    for (int off=1; off<32; off<<=1){ s1 += __shfl_xor(s1,off); s2 += __shfl_xor(s2,off); }
    float mean = s1*(1.f/128.f);
    float var  = s2*(1.f/128.f) - mean*mean;
    float rstd = rsqrtf(var + 1e-5f);
    float4 w4 = *(const float4*)(lnw+col);
    float4 b4 = *(const float4*)(lnb+col);
    float4 o;
    o.x = (v.x-mean)*rstd*w4.x + b4.x;
    o.y = (v.y-mean)*rstd*w4.y + b4.y;
    o.z = (v.z-mean)*rstd*w4.z + b4.z;
    o.w = (v.w-mean)*rstd*w4.w + b4.w;
    *(float4*)&xsl[row][col] = o;
  }
  __syncthreads();
  int j = tid & 127;
  int rg = tid >> 7;            // 0..1, rows rg*4..rg*4+3
  bool hasQK = (j < 127);
  const float* wqr = Wq + (size_t)(hasQK ? j : 126)*128;
  const float* wkr = Wk + (size_t)(hasQK ? j : 126)*128;
  const float* wvr = Wv + (size_t)j*128;
  const float* wgr = Wg + (size_t)j*128;
  float aq[4]={0,0,0,0}, ak[4]={0,0,0,0}, av[4]={0,0,0,0}, ag[4]={0,0,0,0};
  for (int k=0; k<128; k++){
    float wq = wqr[k], wk = wkr[k], wv = wvr[k], wg = wgr[k];
    #pragma unroll
    for (int rr=0; rr<4; rr++){
      float x = xsl[rg*4+rr][k];
      aq[rr] += x*wq; ak[rr] += x*wk; av[rr] += x*wv; ag[rr] += x*wg;
    }
  }
  float gb = Wgb[j];
  #pragma unroll
  for (int rr=0; rr<4; rr++){
    long r = r0 + rg*4 + rr;
    g_Qp[r*128+j] = hasQK ? phi_f(aq[rr]) : 0.f;
    g_Kp[r*128+j] = hasQK ? phi_f(ak[rr]) : 0.f;
    g_Vg[r*128+j] = av[rr]*sigm_f(ag[rr]+gb);
  }
}

// Per-chunk state sums: Ssum[b][c][h][m] = sum_t Kp*Vg ; Sk[b][c][h] = sum_t Kp.
__global__ __launch_bounds__(256) void k2_chunksum()
{
  __shared__ float vgs[16][128];
  __shared__ float kps[16][32];
  int tid = threadIdx.x;
  int ht = blockIdx.x & 3;
  int c  = (blockIdx.x >> 2) & 31;
  int b  = blockIdx.x >> 7;
  int hl = tid >> 3, mg = tid & 7, m0 = mg << 4;
  int h  = ht*32 + hl;
  float acc[16];
  #pragma unroll
  for (int i=0;i<16;i++) acc[i]=0.f;
  float sk = 0.f;
  long base = ((long)b*TT + c*128)*128;
  for (int tb=0; tb<8; tb++){
    __syncthreads();
    { int e = tid*8; int ts = e >> 7; int cc = e & 127;
      const float* s = g_Vg + base + (long)(tb*16+ts)*128 + cc;
      *(float4*)&vgs[ts][cc]   = *(const float4*)s;
      *(float4*)&vgs[ts][cc+4] = *(const float4*)(s+4); }
    { int e = tid*2; int ts = e >> 5; int hh = e & 31;
      const float* s = g_Kp + base + (long)(tb*16+ts)*128 + ht*32 + hh;
      kps[ts][hh] = s[0]; kps[ts][hh+1] = s[1]; }
    __syncthreads();
    for (int ts=0; ts<16; ts++){
      float kp = kps[ts][hl];
      sk += kp;
      #pragma unroll
      for (int i=0;i<16;i++) acc[i] += kp * vgs[ts][m0+i];
    }
  }
  long so = (((long)b*NCH + c)*128 + h)*128 + m0;
  #pragma unroll
  for (int i=0;i<16;i+=4)
    *(float4*)(g_Ssum + so + i) = make_float4(acc[i],acc[i+1],acc[i+2],acc[i+3]);
  if (mg==0) g_Sk[((long)b*NCH + c)*128 + h] = sk;
}

// Exclusive prefix scan over chunks for Ssum (16384 elems/chunk) and Sk.
__global__ __launch_bounds__(256) void k3_scan()
{
  int blk = blockIdx.x % 65;
  int b   = blockIdx.x / 65;
  if (blk < 64){
    int e = blk*256 + threadIdx.x;
    float a = 0.f;
    for (int c=0;c<NCH;c++){
      long idx = ((long)b*NCH + c)*16384 + e;
      g_Spre[idx] = a;
      a += g_Ssum[idx];
    }
  } else if (threadIdx.x < 128){
    int e = threadIdx.x;
    float a = 0.f;
    for (int c=0;c<NCH;c++){
      long idx = ((long)b*NCH + c)*128 + e;
      g_Skp[idx] = a;
      a += g_Sk[idx];
    }
  }
}

// Inter-chunk: numb = Qp @ Spre ; denb = Qp . Skpre  (prefix state in LDS).
__global__ __launch_bounds__(256) void k3b_inter()
{
  __shared__ float spl[16384];      // 64 KB
  __shared__ float qpl[128*132];    // 66 KB (padded stride 132)
  __shared__ float skl[128];
  int tid = threadIdx.x;
  int c = blockIdx.x & 31;
  int b = blockIdx.x >> 5;
  long sbase = ((long)b*NCH + c)*16384;
  for (int i=0;i<16;i++){
    int e = i*1024 + tid*4;
    *(float4*)&spl[e] = *(const float4*)(g_Spre + sbase + e);
  }
  if (tid < 128) skl[tid] = g_Skp[((long)b*NCH + c)*128 + tid];
  long cbase = ((long)b*TT + c*128)*128;
  for (int i=0;i<16;i++){
    int e = i*1024 + tid*4;
    int row = e >> 7, cc = e & 127;
    *(float4*)&qpl[row*132+cc] = *(const float4*)(g_Qp + cbase + e);
  }
  __syncthreads();
  int tq = tid >> 1, mh = tid & 1, m0 = mh*64;
  float acc[64];
  #pragma unroll
  for (int i=0;i<64;i++) acc[i]=0.f;
  float den = 0.f;
  for (int h=0;h<128;h++){
    float q = qpl[tq*132+h];
    den += q * skl[h];
    const float4* sp = (const float4*)&spl[h*128 + m0];
    #pragma unroll
    for (int j=0;j<16;j++){
      float4 s = sp[j];
      acc[4*j+0] += q*s.x; acc[4*j+1] += q*s.y; acc[4*j+2] += q*s.z; acc[4*j+3] += q*s.w;
    }
  }
  long trow = (long)b*TT + c*128 + tq;
  #pragma unroll
  for (int j=0;j<64;j+=4)
    *(float4*)(g_numb + trow*128 + m0 + j) = make_float4(acc[j],acc[j+1],acc[j+2],acc[j+3]);
  if (mh==0) g_denb[trow] = den;
}

// Intra-chunk attention + Wo + residual + LN2, tokens updated IN PLACE.
// ONE BLOCK PER (b, chunk) — 128 rows, 256 threads = 128 rows x 2 col-halves.
// tq_l = tid>>1 in [0,128) is exactly the chunk-local row; no OOB possible.
__global__ __launch_bounds__(256) void k4_attn(
    const float* __restrict__ Wo,
    const float* __restrict__ ln2w, const float* __restrict__ ln2b)
{
  __shared__ float ktl[128*132];   // Kp^T -> Vg -> Wo (67.6 KB)
  __shared__ float bufb[128*132];  // Qp rows -> A -> attn (67.6 KB)
  __shared__ float denl[128];
  int tid = threadIdx.x;
  int c = blockIdx.x & 31;
  int b = blockIdx.x >> 5;
  long cbase = ((long)b*TT + c*128)*128;
  // All 128 Qp rows -> bufb (stride 132)
  for (int i=0;i<16;i++){
    int e = i*1024 + tid*4;
    int row = e >> 7, cc = e & 127;
    *(float4*)&bufb[row*132+cc] = *(const float4*)(g_Qp + cbase + e);
  }
  // Kp^T (h-major) -> ktl
  for (int i=0;i<16;i++){
    int e = i*1024 + tid*4;
    int ts = e >> 7, hh = e & 127;
    float4 k4v = *(const float4*)(g_Kp + cbase + e);
    ktl[(hh+0)*132+ts] = k4v.x;
    ktl[(hh+1)*132+ts] = k4v.y;
    ktl[(hh+2)*132+ts] = k4v.z;
    ktl[(hh+3)*132+ts] = k4v.w;
  }
  __syncthreads();
  int tq_l = tid >> 1, sh = tid & 1, s0 = sh*64;
  float acc[64];
  #pragma unroll
  for (int i=0;i<64;i++) acc[i]=0.f;
  for (int h=0;h<128;h++){
    float q = bufb[tq_l*132+h];
    const float4* kt = (const float4*)&ktl[h*132+s0];
    #pragma unroll
    for (int j=0;j<16;j++){
      float4 k4v = kt[j];
      acc[4*j+0]+=q*k4v.x; acc[4*j+1]+=q*k4v.y; acc[4*j+2]+=q*k4v.z; acc[4*j+3]+=q*k4v.w;
    }
  }
  // causal mask (inclusive, chunk-local) + intra denominator
  float den = 0.f;
  #pragma unroll
  for (int j=0;j<64;j++){
    int ts = s0 + j;
    acc[j] = (ts <= tq_l) ? acc[j] : 0.f;
    den += acc[j];
  }
  den += __shfl_xor(den, 1);
  __syncthreads();
  // A -> bufb ; Vg -> ktl (flat)
  #pragma unroll
  for (int j=0;j<64;j+=4)
    *(float4*)&bufb[tq_l*132 + s0 + j] = make_float4(acc[j],acc[j+1],acc[j+2],acc[j+3]);
  if (sh==0) denl[tq_l] = den;
  for (int i=0;i<16;i++){
    int e = i*1024 + tid*4;
    *(float4*)&ktl[e] = *(const float4*)(g_Vg + cbase + e);
  }
  __syncthreads();
  long trow = (long)b*TT + c*128 + tq_l;
  float acc2[64];
  #pragma unroll
  for (int j=0;j<64;j+=4){
    float4 n4 = *(const float4*)(g_numb + trow*128 + s0 + j);
    acc2[j]=n4.x; acc2[j+1]=n4.y; acc2[j+2]=n4.z; acc2[j+3]=n4.w;
  }
  for (int ts=0; ts<128; ts++){
    float a = bufb[tq_l*132+ts];
    const float4* vv = (const float4*)&ktl[ts*128 + s0];
    #pragma unroll
    for (int j=0;j<16;j++){
      float4 v4 = vv[j];
      acc2[4*j+0]+=a*v4.x; acc2[4*j+1]+=a*v4.y; acc2[4*j+2]+=a*v4.z; acc2[4*j+3]+=a*v4.w;
    }
  }
  float dent = denl[tq_l] + g_denb[trow];
  float inv = 1.f / fmaxf(dent, 1e-6f);
  __syncthreads();
  // attn -> bufb ; Wo -> ktl (flat)
  #pragma unroll
  for (int j=0;j<64;j+=4)
    *(float4*)&bufb[tq_l*132 + s0 + j] =
      make_float4(acc2[j]*inv, acc2[j+1]*inv, acc2[j+2]*inv, acc2[j+3]*inv);
  for (int i=0;i<16;i++){
    int e = i*1024 + tid*4;
    *(float4*)&ktl[e] = *(const float4*)(Wo + e);
  }
  __syncthreads();
  float outv[64];
  const float4* atr = (const float4*)&bufb[tq_l*132];
  for (int jn=0; jn<64; jn++){
    int n = s0 + jn;
    const float4* wr = (const float4*)&ktl[n*128];
    float s = 0.f;
    #pragma unroll
    for (int m=0;m<32;m++){
      float4 a4 = atr[m]; float4 w4 = wr[m];
      s += a4.x*w4.x + a4.y*w4.y + a4.z*w4.z + a4.w*w4.w;
    }
    outv[jn] = g_tok[trow*128+n] + 0.1f*s;
  }
  float s1=0.f, s2=0.f;
  #pragma unroll
  for (int jn=0;jn<64;jn++){ s1 += outv[jn]; s2 += outv[jn]*outv[jn]; }
  s1 += __shfl_xor(s1,1); s2 += __shfl_xor(s2,1);
  float mean = s1*(1.f/128.f);
  float var  = s2*(1.f/128.f) - mean*mean;
  float rstd = rsqrtf(var + 1e-5f);
  #pragma unroll
  for (int j=0;j<64;j+=4){
    int n = s0 + j;
    float4 w4 = *(const float4*)(ln2w+n);
    float4 b4 = *(const float4*)(ln2b+n);
    float4 o;
    o.x = (outv[j+0]-mean)*rstd*w4.x + b4.x;
    o.y = (outv[j+1]-mean)*rstd*w4.y + b4.y;
    o.z = (outv[j+2]-mean)*rstd*w4.z + b4.z;
    o.w = (outv[j+3]-mean)*rstd*w4.w + b4.w;
    *(float4*)(g_tok + trow*128 + n) = o;
  }
}

__global__ __launch_bounds__(128) void k5_pred(const float* __restrict__ pw,
                                               float* __restrict__ out){
  __shared__ float red[2];
  int b = blockIdx.x, tid = threadIdx.x;
  float v = g_tok[((long)b*TT + TT-1)*128 + tid] * pw[tid];
  #pragma unroll
  for (int off=1; off<64; off<<=1) v += __shfl_xor(v, off);
  if ((tid & 63) == 0) red[tid>>6] = v;
  __syncthreads();
  if (tid==0) out[b] = red[0] + red[1];
}

extern "C" void kernel_launch(void* const* d_in, const int* in_sizes, int n_in,
                              void* d_out, int out_size, void* d_ws, size_t ws_size,
                              hipStream_t stream)
{
  (void)in_sizes; (void)n_in; (void)out_size; (void)d_ws; (void)ws_size;
  const float* xs   = (const float*)d_in[0];
  const float* ys   = (const float*)d_in[1];
  const float* qx   = (const float*)d_in[2];
  const float* Wq   = (const float*)d_in[3];
  const float* Wk   = (const float*)d_in[4];
  const float* Wv   = (const float*)d_in[5];
  const float* Wgw  = (const float*)d_in[6];
  const float* Wgb  = (const float*)d_in[7];
  const float* Wo   = (const float*)d_in[8];
  const float* ln1w = (const float*)d_in[9];
  const float* ln1b = (const float*)d_in[10];
  const float* ln2w = (const float*)d_in[11];
  const float* ln2b = (const float*)d_in[12];
  const float* predw= (const float*)d_in[13];

  k0_build<<<4096, 256, 0, stream>>>(xs, ys, qx);

  for (int l=0; l<2; l++){
    const float* Wq_l  = Wq  + (size_t)l*127*128;
    const float* Wk_l  = Wk  + (size_t)l*127*128;
    const float* Wv_l  = Wv  + (size_t)l*128*128;
    const float* Wgw_l = Wgw + (size_t)l*128*128;
    const float* Wgb_l = Wgb + (size_t)l*128;
    const float* Wo_l  = Wo  + (size_t)l*128*128;
    const float* l1w = ln1w + (size_t)l*128;
    const float* l1b = ln1b + (size_t)l*128;
    const float* l2w = ln2w + (size_t)l*128;
    const float* l2b = ln2b + (size_t)l*128;

    k1_ln_qkvg<<<1024, 256, 0, stream>>>(Wq_l, Wk_l, Wv_l, Wgw_l, Wgb_l, l1w, l1b);
    k2_chunksum<<<256, 256, 0, stream>>>();
    k3_scan<<<130, 256, 0, stream>>>();
    k3b_inter<<<64, 256, 0, stream>>>();
    k4_attn<<<64, 256, 0, stream>>>(Wo_l, l2w, l2b);
  }
  k5_pred<<<BB, 128, 0, stream>>>(predw, (float*)d_out);
}

// Round 8
// 417.607 us; speedup vs baseline: 1.6569x; 1.6569x over previous
//
#include <hip/hip_runtime.h>
#include <hip/hip_bf16.h>

#define TT 4096
#define NCH 32
#define BB 2

// Intermediates in static device globals. Every element read is written
// earlier in the same launch.
__device__ float g_tok[(size_t)BB*TT*128];
__device__ float g_Qp [(size_t)BB*TT*128];
__device__ float g_Kp [(size_t)BB*TT*128];
__device__ float g_Vg [(size_t)BB*TT*128];
__device__ float g_Ssum[(size_t)BB*NCH*16384];
__device__ float g_Spre[(size_t)BB*NCH*16384];
__device__ float g_Sk [(size_t)BB*NCH*128];
__device__ float g_Skp[(size_t)BB*NCH*128];

__device__ __forceinline__ float phi_f(float x){ return x > 0.f ? x + 1.f : __expf(x); }
__device__ __forceinline__ float sigm_f(float x){ return 1.f/(1.f+__expf(-x)); }

// Build tokens: [xs, ys] rows + [query_x, 0] final row.
__global__ __launch_bounds__(256) void k0_build(const float* __restrict__ xs,
                                                const float* __restrict__ ys,
                                                const float* __restrict__ qx){
  long e = (long)blockIdx.x * 256 + threadIdx.x;
  int col = (int)(e & 127);
  long r = e >> 7;
  int t = (int)(r & (TT-1));
  int b = (int)(r >> 12);
  float v;
  if (t < TT-1) {
    v = (col < 127) ? xs[((long)b*(TT-1) + t)*127 + col] : ys[(long)b*(TT-1) + t];
  } else {
    v = (col < 127) ? qx[(long)b*127 + col] : 0.f;
  }
  g_tok[e] = v;
}

// LN1 + Q/K/V/G projections + phi/gating. 8 rows per block.
__global__ __launch_bounds__(256) void k1_ln_qkvg(
    const float* __restrict__ Wq, const float* __restrict__ Wk,
    const float* __restrict__ Wv, const float* __restrict__ Wg,
    const float* __restrict__ Wgb,
    const float* __restrict__ lnw, const float* __restrict__ lnb)
{
  __shared__ float xsl[8][128];
  int tid = threadIdx.x;
  long r0 = (long)blockIdx.x * 8;
  {
    int row = tid >> 5;
    int col = (tid & 31) << 2;
    float4 v = *(const float4*)(g_tok + (r0 + row)*128 + col);
    float s1 = v.x+v.y+v.z+v.w;
    float s2 = v.x*v.x+v.y*v.y+v.z*v.z+v.w*v.w;
    #pragma unroll
    for (int off=1; off<32; off<<=1){ s1 += __shfl_xor(s1,off); s2 += __shfl_xor(s2,off); }
    float mean = s1*(1.f/128.f);
    float var  = s2*(1.f/128.f) - mean*mean;
    float rstd = rsqrtf(var + 1e-5f);
    float4 w4 = *(const float4*)(lnw+col);
    float4 b4 = *(const float4*)(lnb+col);
    float4 o;
    o.x = (v.x-mean)*rstd*w4.x + b4.x;
    o.y = (v.y-mean)*rstd*w4.y + b4.y;
    o.z = (v.z-mean)*rstd*w4.z + b4.z;
    o.w = (v.w-mean)*rstd*w4.w + b4.w;
    *(float4*)&xsl[row][col] = o;
  }
  __syncthreads();
  int j = tid & 127;
  int rg = tid >> 7;
  bool hasQK = (j < 127);
  const float* wqr = Wq + (size_t)(hasQK ? j : 126)*128;
  const float* wkr = Wk + (size_t)(hasQK ? j : 126)*128;
  const float* wvr = Wv + (size_t)j*128;
  const float* wgr = Wg + (size_t)j*128;
  float aq[4]={0,0,0,0}, ak[4]={0,0,0,0}, av[4]={0,0,0,0}, ag[4]={0,0,0,0};
  for (int k=0; k<128; k++){
    float wq = wqr[k], wk = wkr[k], wv = wvr[k], wg = wgr[k];
    #pragma unroll
    for (int rr=0; rr<4; rr++){
      float x = xsl[rg*4+rr][k];
      aq[rr] += x*wq; ak[rr] += x*wk; av[rr] += x*wv; ag[rr] += x*wg;
    }
  }
  float gb = Wgb[j];
  #pragma unroll
  for (int rr=0; rr<4; rr++){
    long r = r0 + rg*4 + rr;
    g_Qp[r*128+j] = hasQK ? phi_f(aq[rr]) : 0.f;
    g_Kp[r*128+j] = hasQK ? phi_f(ak[rr]) : 0.f;
    g_Vg[r*128+j] = av[rr]*sigm_f(ag[rr]+gb);
  }
}

// Per-chunk state sums: Ssum[b][c][h][m] = sum_t Kp*Vg ; Sk[b][c][h] = sum_t Kp.
__global__ __launch_bounds__(256) void k2_chunksum()
{
  __shared__ float vgs[16][128];
  __shared__ float kps[16][32];
  int tid = threadIdx.x;
  int ht = blockIdx.x & 3;
  int c  = (blockIdx.x >> 2) & 31;
  int b  = blockIdx.x >> 7;
  int hl = tid >> 3, mg = tid & 7, m0 = mg << 4;
  int h  = ht*32 + hl;
  float acc[16];
  #pragma unroll
  for (int i=0;i<16;i++) acc[i]=0.f;
  float sk = 0.f;
  long base = ((long)b*TT + c*128)*128;
  for (int tb=0; tb<8; tb++){
    __syncthreads();
    { int e = tid*8; int ts = e >> 7; int cc = e & 127;
      const float* s = g_Vg + base + (long)(tb*16+ts)*128 + cc;
      *(float4*)&vgs[ts][cc]   = *(const float4*)s;
      *(float4*)&vgs[ts][cc+4] = *(const float4*)(s+4); }
    { int e = tid*2; int ts = e >> 5; int hh = e & 31;
      const float* s = g_Kp + base + (long)(tb*16+ts)*128 + ht*32 + hh;
      kps[ts][hh] = s[0]; kps[ts][hh+1] = s[1]; }
    __syncthreads();
    for (int ts=0; ts<16; ts++){
      float kp = kps[ts][hl];
      sk += kp;
      #pragma unroll
      for (int i=0;i<16;i++) acc[i] += kp * vgs[ts][m0+i];
    }
  }
  long so = (((long)b*NCH + c)*128 + h)*128 + m0;
  #pragma unroll
  for (int i=0;i<16;i+=4)
    *(float4*)(g_Ssum + so + i) = make_float4(acc[i],acc[i+1],acc[i+2],acc[i+3]);
  if (mg==0) g_Sk[((long)b*NCH + c)*128 + h] = sk;
}

// Exclusive prefix scan over chunks for Ssum and Sk.
__global__ __launch_bounds__(256) void k3_scan()
{
  int blk = blockIdx.x % 65;
  int b   = blockIdx.x / 65;
  if (blk < 64){
    int e = blk*256 + threadIdx.x;
    float a = 0.f;
    for (int c=0;c<NCH;c++){
      long idx = ((long)b*NCH + c)*16384 + e;
      g_Spre[idx] = a;
      a += g_Ssum[idx];
    }
  } else if (threadIdx.x < 128){
    int e = threadIdx.x;
    float a = 0.f;
    for (int c=0;c<NCH;c++){
      long idx = ((long)b*NCH + c)*128 + e;
      g_Skp[idx] = a;
      a += g_Sk[idx];
    }
  }
}

// Fused inter+intra attention + Wo + residual + LN2, in place on g_tok.
// Grid: BB*NCH*4 = 256 blocks; block owns 32 rows of one chunk.
// Thread: row_l = tid>>3 (0..31), cg = tid&7; cols n = cg*4 + 32*j + k.
__global__ __launch_bounds__(256) void k4_fused(
    const float* __restrict__ Wo,
    const float* __restrict__ ln2w, const float* __restrict__ ln2b)
{
  __shared__ float spl[16384];     // Spre[b][c] h-major [h*128+n]   (64 KB)
  __shared__ float ktl[128*132];   // K^T [h][ts] -> Vg flat -> Wo^T [m][n] (67.6 KB)
  __shared__ float bufb[32*132];   // Qp rows -> A rows -> attn rows (16.9 KB)
  __shared__ float skl[128];
  int tid = threadIdx.x;
  int rq = blockIdx.x & 3;
  int c  = (blockIdx.x >> 2) & 31;
  int b  = blockIdx.x >> 7;
  int r0 = rq*32;
  long cbase = ((long)b*TT + c*128)*128;
  long sbase = ((long)b*NCH + c)*16384;

  // ---- stage: Spre (direct), Skp, Qp rows (direct), K^T (lane-diagonal, conflict-free)
  for (int i=0;i<16;i++){
    int e = i*1024 + tid*4;
    *(float4*)&spl[e] = *(const float4*)(g_Spre + sbase + e);
  }
  if (tid < 128) skl[tid] = g_Skp[((long)b*NCH + c)*128 + tid];
  for (int i=0;i<4;i++){
    int e = i*1024 + tid*4;
    int row = e >> 7, cc = e & 127;
    *(float4*)&bufb[row*132+cc] = *(const float4*)(g_Qp + cbase + (long)(r0+row)*128 + cc);
  }
  for (int i=0;i<16;i++){
    int ts = (tid & 31) + 32*(i & 3);
    int hc = (tid >> 5) + 8*(i >> 2);
    float4 v = *(const float4*)(g_Kp + cbase + (long)ts*128 + hc*4);
    ktl[(hc*4+0)*132 + ts] = v.x;
    ktl[(hc*4+1)*132 + ts] = v.y;
    ktl[(hc*4+2)*132 + ts] = v.z;
    ktl[(hc*4+3)*132 + ts] = v.w;
  }
  __syncthreads();

  int row_l = tid >> 3, cg = tid & 7;
  int tq = r0 + row_l;               // chunk-local causal index
  long trow = (long)b*TT + c*128 + tq;
  float acc2[16], a[16];
  #pragma unroll
  for (int i=0;i<16;i++){ acc2[i]=0.f; a[i]=0.f; }
  float den_i = 0.f;
  // Phase A: inter GEMM (Qp@Spre) + intra QK^T + den_inter, one h-loop
  for (int h=0;h<128;h++){
    float qv = bufb[row_l*132 + h];
    den_i += qv * skl[h];
    #pragma unroll
    for (int j=0;j<4;j++){
      float4 s4 = *(const float4*)&spl[h*128 + cg*4 + 32*j];
      float4 k4 = *(const float4*)&ktl[h*132 + cg*4 + 32*j];
      acc2[4*j+0] += qv*s4.x; acc2[4*j+1] += qv*s4.y; acc2[4*j+2] += qv*s4.z; acc2[4*j+3] += qv*s4.w;
      a[4*j+0]    += qv*k4.x; a[4*j+1]    += qv*k4.y; a[4*j+2]    += qv*k4.z; a[4*j+3]    += qv*k4.w;
    }
  }
  // causal mask (inclusive, chunk-local) + intra denominator
  float den_a = 0.f;
  #pragma unroll
  for (int j=0;j<4;j++){
    #pragma unroll
    for (int k=0;k<4;k++){
      int ts = cg*4 + 32*j + k;
      if (ts > tq) a[4*j+k] = 0.f;
      den_a += a[4*j+k];
    }
  }
  den_a += __shfl_xor(den_a, 1);
  den_a += __shfl_xor(den_a, 2);
  den_a += __shfl_xor(den_a, 4);
  float inv = 1.f / fmaxf(den_i + den_a, 1e-6f);
  __syncthreads();
  // A -> bufb ; Vg -> ktl flat [ts*128+n]
  #pragma unroll
  for (int j=0;j<4;j++)
    *(float4*)&bufb[row_l*132 + cg*4 + 32*j] = make_float4(a[4*j],a[4*j+1],a[4*j+2],a[4*j+3]);
  for (int i=0;i<16;i++){
    int e = i*1024 + tid*4;
    *(float4*)&ktl[e] = *(const float4*)(g_Vg + cbase + e);
  }
  __syncthreads();
  // PV: acc2 += A @ Vg
  for (int ts=0; ts<128; ts++){
    float av = bufb[row_l*132 + ts];
    #pragma unroll
    for (int j=0;j<4;j++){
      float4 v4 = *(const float4*)&ktl[ts*128 + cg*4 + 32*j];
      acc2[4*j+0]+=av*v4.x; acc2[4*j+1]+=av*v4.y; acc2[4*j+2]+=av*v4.z; acc2[4*j+3]+=av*v4.w;
    }
  }
  __syncthreads();
  // attn -> bufb ; Wo^T -> ktl [m][n] str132 (lane-diagonal, conflict-free)
  #pragma unroll
  for (int j=0;j<4;j++)
    *(float4*)&bufb[row_l*132 + cg*4 + 32*j] =
      make_float4(acc2[4*j]*inv, acc2[4*j+1]*inv, acc2[4*j+2]*inv, acc2[4*j+3]*inv);
  for (int i=0;i<16;i++){
    int n  = (tid & 31) + 32*(i & 3);
    int mc = (tid >> 5) + 8*(i >> 2);
    float4 v = *(const float4*)(Wo + (long)n*128 + mc*4);
    ktl[(mc*4+0)*132 + n] = v.x;
    ktl[(mc*4+1)*132 + n] = v.y;
    ktl[(mc*4+2)*132 + n] = v.z;
    ktl[(mc*4+3)*132 + n] = v.w;
  }
  __syncthreads();
  // out = attn @ Wo^T (+residual), then LN2
  float s[16];
  #pragma unroll
  for (int i=0;i<16;i++) s[i]=0.f;
  for (int m=0;m<128;m++){
    float av = bufb[row_l*132 + m];
    #pragma unroll
    for (int j=0;j<4;j++){
      float4 w4 = *(const float4*)&ktl[m*132 + cg*4 + 32*j];
      s[4*j+0]+=av*w4.x; s[4*j+1]+=av*w4.y; s[4*j+2]+=av*w4.z; s[4*j+3]+=av*w4.w;
    }
  }
  float outv[16];
  float s1=0.f, s2=0.f;
  #pragma unroll
  for (int j=0;j<4;j++){
    float4 t4 = *(const float4*)(g_tok + trow*128 + cg*4 + 32*j);
    outv[4*j+0] = t4.x + 0.1f*s[4*j+0];
    outv[4*j+1] = t4.y + 0.1f*s[4*j+1];
    outv[4*j+2] = t4.z + 0.1f*s[4*j+2];
    outv[4*j+3] = t4.w + 0.1f*s[4*j+3];
  }
  #pragma unroll
  for (int i=0;i<16;i++){ s1 += outv[i]; s2 += outv[i]*outv[i]; }
  s1 += __shfl_xor(s1,1); s2 += __shfl_xor(s2,1);
  s1 += __shfl_xor(s1,2); s2 += __shfl_xor(s2,2);
  s1 += __shfl_xor(s1,4); s2 += __shfl_xor(s2,4);
  float mean = s1*(1.f/128.f);
  float var  = s2*(1.f/128.f) - mean*mean;
  float rstd = rsqrtf(var + 1e-5f);
  #pragma unroll
  for (int j=0;j<4;j++){
    int n = cg*4 + 32*j;
    float4 w4 = *(const float4*)(ln2w+n);
    float4 b4 = *(const float4*)(ln2b+n);
    float4 o;
    o.x = (outv[4*j+0]-mean)*rstd*w4.x + b4.x;
    o.y = (outv[4*j+1]-mean)*rstd*w4.y + b4.y;
    o.z = (outv[4*j+2]-mean)*rstd*w4.z + b4.z;
    o.w = (outv[4*j+3]-mean)*rstd*w4.w + b4.w;
    *(float4*)(g_tok + trow*128 + n) = o;
  }
}

__global__ __launch_bounds__(128) void k5_pred(const float* __restrict__ pw,
                                               float* __restrict__ out){
  __shared__ float red[2];
  int b = blockIdx.x, tid = threadIdx.x;
  float v = g_tok[((long)b*TT + TT-1)*128 + tid] * pw[tid];
  #pragma unroll
  for (int off=1; off<64; off<<=1) v += __shfl_xor(v, off);
  if ((tid & 63) == 0) red[tid>>6] = v;
  __syncthreads();
  if (tid==0) out[b] = red[0] + red[1];
}

extern "C" void kernel_launch(void* const* d_in, const int* in_sizes, int n_in,
                              void* d_out, int out_size, void* d_ws, size_t ws_size,
                              hipStream_t stream)
{
  (void)in_sizes; (void)n_in; (void)out_size; (void)d_ws; (void)ws_size;
  const float* xs   = (const float*)d_in[0];
  const float* ys   = (const float*)d_in[1];
  const float* qx   = (const float*)d_in[2];
  const float* Wq   = (const float*)d_in[3];
  const float* Wk   = (const float*)d_in[4];
  const float* Wv   = (const float*)d_in[5];
  const float* Wgw  = (const float*)d_in[6];
  const float* Wgb  = (const float*)d_in[7];
  const float* Wo   = (const float*)d_in[8];
  const float* ln1w = (const float*)d_in[9];
  const float* ln1b = (const float*)d_in[10];
  const float* ln2w = (const float*)d_in[11];
  const float* ln2b = (const float*)d_in[12];
  const float* predw= (const float*)d_in[13];

  k0_build<<<4096, 256, 0, stream>>>(xs, ys, qx);

  for (int l=0; l<2; l++){
    const float* Wq_l  = Wq  + (size_t)l*127*128;
    const float* Wk_l  = Wk  + (size_t)l*127*128;
    const float* Wv_l  = Wv  + (size_t)l*128*128;
    const float* Wgw_l = Wgw + (size_t)l*128*128;
    const float* Wgb_l = Wgb + (size_t)l*128;
    const float* Wo_l  = Wo  + (size_t)l*128*128;
    const float* l1w = ln1w + (size_t)l*128;
    const float* l1b = ln1b + (size_t)l*128;
    const float* l2w = ln2w + (size_t)l*128;
    const float* l2b = ln2b + (size_t)l*128;

    k1_ln_qkvg<<<1024, 256, 0, stream>>>(Wq_l, Wk_l, Wv_l, Wgw_l, Wgb_l, l1w, l1b);
    k2_chunksum<<<256, 256, 0, stream>>>();
    k3_scan<<<130, 256, 0, stream>>>();
    k4_fused<<<256, 256, 0, stream>>>(Wo_l, l2w, l2b);
  }
  k5_pred<<<BB, 128, 0, stream>>>(predw, (float*)d_out);
}

// Round 9
// 252.272 us; speedup vs baseline: 2.7428x; 1.6554x over previous
//
#include <hip/hip_runtime.h>
#include <hip/hip_bf16.h>

#define TT 4096
#define NCH 32
#define BB 2

// Intermediates in static device globals. Every element read is written
// earlier in the same launch.
__device__ float g_tok[(size_t)BB*TT*128];
__device__ float g_xn [(size_t)BB*TT*128];
__device__ float g_Qp [(size_t)BB*TT*128];
__device__ float g_Kp [(size_t)BB*TT*128];
__device__ float g_Vg [(size_t)BB*TT*128];
__device__ float g_Pv [(size_t)BB*TT*128];
__device__ float g_Pg [(size_t)BB*TT*128];
__device__ float g_Ssum[(size_t)BB*NCH*16384];
__device__ float g_Spre[(size_t)BB*NCH*16384];
__device__ float g_Sk [(size_t)BB*NCH*128];
__device__ float g_Skp[(size_t)BB*NCH*128];

__device__ __forceinline__ float phi_f(float x){ return x > 0.f ? x + 1.f : __expf(x); }
__device__ __forceinline__ float sigm_f(float x){ return 1.f/(1.f+__expf(-x)); }

// Build tokens: [xs, ys] rows + [query_x, 0] final row.
__global__ __launch_bounds__(256) void k0_build(const float* __restrict__ xs,
                                                const float* __restrict__ ys,
                                                const float* __restrict__ qx){
  long e = (long)blockIdx.x * 256 + threadIdx.x;
  int col = (int)(e & 127);
  long r = e >> 7;
  int t = (int)(r & (TT-1));
  int b = (int)(r >> 12);
  float v;
  if (t < TT-1) {
    v = (col < 127) ? xs[((long)b*(TT-1) + t)*127 + col] : ys[(long)b*(TT-1) + t];
  } else {
    v = (col < 127) ? qx[(long)b*127 + col] : 0.f;
  }
  g_tok[e] = v;
}

// LN1 -> g_xn. 8 rows/block, 32 lanes per row (row reduce within 32-lane group).
__global__ __launch_bounds__(256) void k1a_ln(const float* __restrict__ lnw,
                                              const float* __restrict__ lnb){
  int tid = threadIdx.x;
  long r0 = (long)blockIdx.x * 8;
  int row = tid >> 5;
  int col = (tid & 31) << 2;
  float4 v = *(const float4*)(g_tok + (r0 + row)*128 + col);
  float s1 = v.x+v.y+v.z+v.w;
  float s2 = v.x*v.x+v.y*v.y+v.z*v.z+v.w*v.w;
  #pragma unroll
  for (int off=1; off<32; off<<=1){ s1 += __shfl_xor(s1,off); s2 += __shfl_xor(s2,off); }
  float mean = s1*(1.f/128.f);
  float var  = s2*(1.f/128.f) - mean*mean;
  float rstd = rsqrtf(var + 1e-5f);
  float4 w4 = *(const float4*)(lnw+col);
  float4 b4 = *(const float4*)(lnb+col);
  float4 o;
  o.x = (v.x-mean)*rstd*w4.x + b4.x;
  o.y = (v.y-mean)*rstd*w4.y + b4.y;
  o.z = (v.z-mean)*rstd*w4.z + b4.z;
  o.w = (v.w-mean)*rstd*w4.w + b4.w;
  *(float4*)(g_xn + (r0 + row)*128 + col) = o;
}

// Projection GEMM: 128 rows x 128 cols per block, k=128.
// grid = (BB*TT/128) * 4 ; mat 0=Q(phi,col127=0) 1=K(phi,col127=0) 2=V(raw) 3=G(raw).
// Tiles staged transposed via lane-diagonal mapping (conflict-free writes).
__global__ __launch_bounds__(256) void k1b_gemm(
    const float* __restrict__ Wq, const float* __restrict__ Wk,
    const float* __restrict__ Wv, const float* __restrict__ Wg)
{
  __shared__ float xt[128*132];   // x^T [k][row]
  __shared__ float wt[128*132];   // W^T [k][j]
  int tid = threadIdx.x;
  int mat = blockIdx.x & 3;
  long row0 = (long)(blockIdx.x >> 2) * 128;
  const float* W = (mat==0) ? Wq : (mat==1) ? Wk : (mat==2) ? Wv : Wg;
  bool isQK = (mat < 2);
  for (int i=0;i<16;i++){
    int ts = (tid & 31) + 32*(i & 3);     // token row in tile
    int hc = (tid >> 5) + 8*(i >> 2);     // k group of 4
    float4 v = *(const float4*)(g_xn + (row0+ts)*128 + hc*4);
    xt[(hc*4+0)*132+ts] = v.x;
    xt[(hc*4+1)*132+ts] = v.y;
    xt[(hc*4+2)*132+ts] = v.z;
    xt[(hc*4+3)*132+ts] = v.w;
  }
  for (int i=0;i<16;i++){
    int ts = (tid & 31) + 32*(i & 3);     // output col j
    int hc = (tid >> 5) + 8*(i >> 2);     // k group of 4
    int wr = isQK ? (ts < 127 ? ts : 126) : ts;   // clamp: avoid OOB on 127-row Wq/Wk
    float4 v = *(const float4*)(W + (long)wr*128 + hc*4);
    wt[(hc*4+0)*132+ts] = v.x;
    wt[(hc*4+1)*132+ts] = v.y;
    wt[(hc*4+2)*132+ts] = v.z;
    wt[(hc*4+3)*132+ts] = v.w;
  }
  __syncthreads();
  int r0 = (tid >> 4) * 8;
  int c0 = (tid & 15) * 8;
  float acc[8][8];
  #pragma unroll
  for (int i=0;i<8;i++)
    #pragma unroll
    for (int j=0;j<8;j++) acc[i][j]=0.f;
  for (int k=0;k<128;k++){
    float4 xa = *(const float4*)&xt[k*132 + r0];
    float4 xb = *(const float4*)&xt[k*132 + r0 + 4];
    float4 wa = *(const float4*)&wt[k*132 + c0];
    float4 wb = *(const float4*)&wt[k*132 + c0 + 4];
    float xr[8] = {xa.x,xa.y,xa.z,xa.w,xb.x,xb.y,xb.z,xb.w};
    float wc[8] = {wa.x,wa.y,wa.z,wa.w,wb.x,wb.y,wb.z,wb.w};
    #pragma unroll
    for (int i=0;i<8;i++)
      #pragma unroll
      for (int j=0;j<8;j++)
        acc[i][j] += xr[i]*wc[j];
  }
  long rbase = row0 + r0;
  if (isQK){
    float* dst = (mat==0) ? g_Qp : g_Kp;
    #pragma unroll
    for (int i=0;i<8;i++){
      float v[8];
      #pragma unroll
      for (int j=0;j<8;j++) v[j] = (c0+j < 127) ? phi_f(acc[i][j]) : 0.f;
      *(float4*)(dst + (rbase+i)*128 + c0)     = make_float4(v[0],v[1],v[2],v[3]);
      *(float4*)(dst + (rbase+i)*128 + c0 + 4) = make_float4(v[4],v[5],v[6],v[7]);
    }
  } else {
    float* dst = (mat==2) ? g_Pv : g_Pg;
    #pragma unroll
    for (int i=0;i<8;i++){
      *(float4*)(dst + (rbase+i)*128 + c0)     = make_float4(acc[i][0],acc[i][1],acc[i][2],acc[i][3]);
      *(float4*)(dst + (rbase+i)*128 + c0 + 4) = make_float4(acc[i][4],acc[i][5],acc[i][6],acc[i][7]);
    }
  }
}

// Vg = Pv * sigmoid(Pg + b), vectorized.
__global__ __launch_bounds__(256) void k1c_vg(const float* __restrict__ Wgb){
  long e = ((long)blockIdx.x*256 + threadIdx.x) * 4;
  int j = (int)(e & 127);
  float4 pv = *(const float4*)(g_Pv + e);
  float4 pg = *(const float4*)(g_Pg + e);
  float4 gb = *(const float4*)(Wgb + j);
  float4 o;
  o.x = pv.x * sigm_f(pg.x + gb.x);
  o.y = pv.y * sigm_f(pg.y + gb.y);
  o.z = pv.z * sigm_f(pg.z + gb.z);
  o.w = pv.w * sigm_f(pg.w + gb.w);
  *(float4*)(g_Vg + e) = o;
}

// Per-chunk state sums: Ssum[b][c][h][m] = sum_t Kp*Vg ; Sk[b][c][h] = sum_t Kp.
__global__ __launch_bounds__(256) void k2_chunksum()
{
  __shared__ float vgs[16][128];
  __shared__ float kps[16][32];
  int tid = threadIdx.x;
  int ht = blockIdx.x & 3;
  int c  = (blockIdx.x >> 2) & 31;
  int b  = blockIdx.x >> 7;
  int hl = tid >> 3, mg = tid & 7, m0 = mg << 4;
  int h  = ht*32 + hl;
  float acc[16];
  #pragma unroll
  for (int i=0;i<16;i++) acc[i]=0.f;
  float sk = 0.f;
  long base = ((long)b*TT + c*128)*128;
  for (int tb=0; tb<8; tb++){
    __syncthreads();
    { int e = tid*8; int ts = e >> 7; int cc = e & 127;
      const float* s = g_Vg + base + (long)(tb*16+ts)*128 + cc;
      *(float4*)&vgs[ts][cc]   = *(const float4*)s;
      *(float4*)&vgs[ts][cc+4] = *(const float4*)(s+4); }
    { int e = tid*2; int ts = e >> 5; int hh = e & 31;
      const float* s = g_Kp + base + (long)(tb*16+ts)*128 + ht*32 + hh;
      kps[ts][hh] = s[0]; kps[ts][hh+1] = s[1]; }
    __syncthreads();
    for (int ts=0; ts<16; ts++){
      float kp = kps[ts][hl];
      sk += kp;
      #pragma unroll
      for (int i=0;i<16;i++) acc[i] += kp * vgs[ts][m0+i];
    }
  }
  long so = (((long)b*NCH + c)*128 + h)*128 + m0;
  #pragma unroll
  for (int i=0;i<16;i+=4)
    *(float4*)(g_Ssum + so + i) = make_float4(acc[i],acc[i+1],acc[i+2],acc[i+3]);
  if (mg==0) g_Sk[((long)b*NCH + c)*128 + h] = sk;
}

// Exclusive prefix scan over chunks for Ssum and Sk.
__global__ __launch_bounds__(256) void k3_scan()
{
  int blk = blockIdx.x % 65;
  int b   = blockIdx.x / 65;
  if (blk < 64){
    int e = blk*256 + threadIdx.x;
    float a = 0.f;
    for (int c=0;c<NCH;c++){
      long idx = ((long)b*NCH + c)*16384 + e;
      g_Spre[idx] = a;
      a += g_Ssum[idx];
    }
  } else if (threadIdx.x < 128){
    int e = threadIdx.x;
    float a = 0.f;
    for (int c=0;c<NCH;c++){
      long idx = ((long)b*NCH + c)*128 + e;
      g_Skp[idx] = a;
      a += g_Sk[idx];
    }
  }
}

// Fused inter+intra attention + Wo + residual + LN2, in place on g_tok.
// Grid: BB*NCH*4 = 256 blocks; block owns 32 rows of one chunk.
__global__ __launch_bounds__(256) void k4_fused(
    const float* __restrict__ Wo,
    const float* __restrict__ ln2w, const float* __restrict__ ln2b)
{
  __shared__ float spl[16384];     // Spre[b][c] h-major [h*128+n]   (64 KB)
  __shared__ float ktl[128*132];   // K^T [h][ts] -> Vg flat -> Wo^T [m][n]
  __shared__ float bufb[32*132];   // Qp rows -> A rows -> attn rows
  __shared__ float skl[128];
  int tid = threadIdx.x;
  int rq = blockIdx.x & 3;
  int c  = (blockIdx.x >> 2) & 31;
  int b  = blockIdx.x >> 7;
  int r0 = rq*32;
  long cbase = ((long)b*TT + c*128)*128;
  long sbase = ((long)b*NCH + c)*16384;

  for (int i=0;i<16;i++){
    int e = i*1024 + tid*4;
    *(float4*)&spl[e] = *(const float4*)(g_Spre + sbase + e);
  }
  if (tid < 128) skl[tid] = g_Skp[((long)b*NCH + c)*128 + tid];
  for (int i=0;i<4;i++){
    int e = i*1024 + tid*4;
    int row = e >> 7, cc = e & 127;
    *(float4*)&bufb[row*132+cc] = *(const float4*)(g_Qp + cbase + (long)(r0+row)*128 + cc);
  }
  for (int i=0;i<16;i++){
    int ts = (tid & 31) + 32*(i & 3);
    int hc = (tid >> 5) + 8*(i >> 2);
    float4 v = *(const float4*)(g_Kp + cbase + (long)ts*128 + hc*4);
    ktl[(hc*4+0)*132 + ts] = v.x;
    ktl[(hc*4+1)*132 + ts] = v.y;
    ktl[(hc*4+2)*132 + ts] = v.z;
    ktl[(hc*4+3)*132 + ts] = v.w;
  }
  __syncthreads();

  int row_l = tid >> 3, cg = tid & 7;
  int tq = r0 + row_l;
  long trow = (long)b*TT + c*128 + tq;
  float acc2[16], a[16];
  #pragma unroll
  for (int i=0;i<16;i++){ acc2[i]=0.f; a[i]=0.f; }
  float den_i = 0.f;
  for (int h=0;h<128;h++){
    float qv = bufb[row_l*132 + h];
    den_i += qv * skl[h];
    #pragma unroll
    for (int j=0;j<4;j++){
      float4 s4 = *(const float4*)&spl[h*128 + cg*4 + 32*j];
      float4 k4 = *(const float4*)&ktl[h*132 + cg*4 + 32*j];
      acc2[4*j+0] += qv*s4.x; acc2[4*j+1] += qv*s4.y; acc2[4*j+2] += qv*s4.z; acc2[4*j+3] += qv*s4.w;
      a[4*j+0]    += qv*k4.x; a[4*j+1]    += qv*k4.y; a[4*j+2]    += qv*k4.z; a[4*j+3]    += qv*k4.w;
    }
  }
  float den_a = 0.f;
  #pragma unroll
  for (int j=0;j<4;j++){
    #pragma unroll
    for (int k=0;k<4;k++){
      int ts = cg*4 + 32*j + k;
      if (ts > tq) a[4*j+k] = 0.f;
      den_a += a[4*j+k];
    }
  }
  den_a += __shfl_xor(den_a, 1);
  den_a += __shfl_xor(den_a, 2);
  den_a += __shfl_xor(den_a, 4);
  float inv = 1.f / fmaxf(den_i + den_a, 1e-6f);
  __syncthreads();
  #pragma unroll
  for (int j=0;j<4;j++)
    *(float4*)&bufb[row_l*132 + cg*4 + 32*j] = make_float4(a[4*j],a[4*j+1],a[4*j+2],a[4*j+3]);
  for (int i=0;i<16;i++){
    int e = i*1024 + tid*4;
    *(float4*)&ktl[e] = *(const float4*)(g_Vg + cbase + e);
  }
  __syncthreads();
  for (int ts=0; ts<128; ts++){
    float av = bufb[row_l*132 + ts];
    #pragma unroll
    for (int j=0;j<4;j++){
      float4 v4 = *(const float4*)&ktl[ts*128 + cg*4 + 32*j];
      acc2[4*j+0]+=av*v4.x; acc2[4*j+1]+=av*v4.y; acc2[4*j+2]+=av*v4.z; acc2[4*j+3]+=av*v4.w;
    }
  }
  __syncthreads();
  #pragma unroll
  for (int j=0;j<4;j++)
    *(float4*)&bufb[row_l*132 + cg*4 + 32*j] =
      make_float4(acc2[4*j]*inv, acc2[4*j+1]*inv, acc2[4*j+2]*inv, acc2[4*j+3]*inv);
  for (int i=0;i<16;i++){
    int n  = (tid & 31) + 32*(i & 3);
    int mc = (tid >> 5) + 8*(i >> 2);
    float4 v = *(const float4*)(Wo + (long)n*128 + mc*4);
    ktl[(mc*4+0)*132 + n] = v.x;
    ktl[(mc*4+1)*132 + n] = v.y;
    ktl[(mc*4+2)*132 + n] = v.z;
    ktl[(mc*4+3)*132 + n] = v.w;
  }
  __syncthreads();
  float s[16];
  #pragma unroll
  for (int i=0;i<16;i++) s[i]=0.f;
  for (int m=0;m<128;m++){
    float av = bufb[row_l*132 + m];
    #pragma unroll
    for (int j=0;j<4;j++){
      float4 w4 = *(const float4*)&ktl[m*132 + cg*4 + 32*j];
      s[4*j+0]+=av*w4.x; s[4*j+1]+=av*w4.y; s[4*j+2]+=av*w4.z; s[4*j+3]+=av*w4.w;
    }
  }
  float outv[16];
  float s1=0.f, s2=0.f;
  #pragma unroll
  for (int j=0;j<4;j++){
    float4 t4 = *(const float4*)(g_tok + trow*128 + cg*4 + 32*j);
    outv[4*j+0] = t4.x + 0.1f*s[4*j+0];
    outv[4*j+1] = t4.y + 0.1f*s[4*j+1];
    outv[4*j+2] = t4.z + 0.1f*s[4*j+2];
    outv[4*j+3] = t4.w + 0.1f*s[4*j+3];
  }
  #pragma unroll
  for (int i=0;i<16;i++){ s1 += outv[i]; s2 += outv[i]*outv[i]; }
  s1 += __shfl_xor(s1,1); s2 += __shfl_xor(s2,1);
  s1 += __shfl_xor(s1,2); s2 += __shfl_xor(s2,2);
  s1 += __shfl_xor(s1,4); s2 += __shfl_xor(s2,4);
  float mean = s1*(1.f/128.f);
  float var  = s2*(1.f/128.f) - mean*mean;
  float rstd = rsqrtf(var + 1e-5f);
  #pragma unroll
  for (int j=0;j<4;j++){
    int n = cg*4 + 32*j;
    float4 w4 = *(const float4*)(ln2w+n);
    float4 b4 = *(const float4*)(ln2b+n);
    float4 o;
    o.x = (outv[4*j+0]-mean)*rstd*w4.x + b4.x;
    o.y = (outv[4*j+1]-mean)*rstd*w4.y + b4.y;
    o.z = (outv[4*j+2]-mean)*rstd*w4.z + b4.z;
    o.w = (outv[4*j+3]-mean)*rstd*w4.w + b4.w;
    *(float4*)(g_tok + trow*128 + n) = o;
  }
}

__global__ __launch_bounds__(128) void k5_pred(const float* __restrict__ pw,
                                               float* __restrict__ out){
  __shared__ float red[2];
  int b = blockIdx.x, tid = threadIdx.x;
  float v = g_tok[((long)b*TT + TT-1)*128 + tid] * pw[tid];
  #pragma unroll
  for (int off=1; off<64; off<<=1) v += __shfl_xor(v, off);
  if ((tid & 63) == 0) red[tid>>6] = v;
  __syncthreads();
  if (tid==0) out[b] = red[0] + red[1];
}

extern "C" void kernel_launch(void* const* d_in, const int* in_sizes, int n_in,
                              void* d_out, int out_size, void* d_ws, size_t ws_size,
                              hipStream_t stream)
{
  (void)in_sizes; (void)n_in; (void)out_size; (void)d_ws; (void)ws_size;
  const float* xs   = (const float*)d_in[0];
  const float* ys   = (const float*)d_in[1];
  const float* qx   = (const float*)d_in[2];
  const float* Wq   = (const float*)d_in[3];
  const float* Wk   = (const float*)d_in[4];
  const float* Wv   = (const float*)d_in[5];
  const float* Wgw  = (const float*)d_in[6];
  const float* Wgb  = (const float*)d_in[7];
  const float* Wo   = (const float*)d_in[8];
  const float* ln1w = (const float*)d_in[9];
  const float* ln1b = (const float*)d_in[10];
  const float* ln2w = (const float*)d_in[11];
  const float* ln2b = (const float*)d_in[12];
  const float* predw= (const float*)d_in[13];

  k0_build<<<4096, 256, 0, stream>>>(xs, ys, qx);

  for (int l=0; l<2; l++){
    const float* Wq_l  = Wq  + (size_t)l*127*128;
    const float* Wk_l  = Wk  + (size_t)l*127*128;
    const float* Wv_l  = Wv  + (size_t)l*128*128;
    const float* Wgw_l = Wgw + (size_t)l*128*128;
    const float* Wgb_l = Wgb + (size_t)l*128;
    const float* Wo_l  = Wo  + (size_t)l*128*128;
    const float* l1w = ln1w + (size_t)l*128;
    const float* l1b = ln1b + (size_t)l*128;
    const float* l2w = ln2w + (size_t)l*128;
    const float* l2b = ln2b + (size_t)l*128;

    k1a_ln<<<1024, 256, 0, stream>>>(l1w, l1b);
    k1b_gemm<<<256, 256, 0, stream>>>(Wq_l, Wk_l, Wv_l, Wgw_l);
    k1c_vg<<<1024, 256, 0, stream>>>(Wgb_l);
    k2_chunksum<<<256, 256, 0, stream>>>();
    k3_scan<<<130, 256, 0, stream>>>();
    k4_fused<<<256, 256, 0, stream>>>(Wo_l, l2w, l2b);
  }
  k5_pred<<<BB, 128, 0, stream>>>(predw, (float*)d_out);
}

// Round 11
// 244.311 us; speedup vs baseline: 2.8322x; 1.0326x over previous
//
#include <hip/hip_runtime.h>
#include <hip/hip_bf16.h>

#define TT 4096
#define NCH 32
#define BB 2

// Intermediates in static device globals. Every element read is written
// earlier in the same launch.
__device__ float g_tok[(size_t)BB*TT*128];
__device__ float g_Qp [(size_t)BB*TT*128];
__device__ float g_Kp [(size_t)BB*TT*128];
__device__ float g_Vg [(size_t)BB*TT*128];
__device__ float g_Pv [(size_t)BB*TT*128];
__device__ float g_Pg [(size_t)BB*TT*128];
__device__ float g_Ssum[(size_t)BB*NCH*16384];
__device__ float g_Spre[(size_t)BB*NCH*16384];
__device__ float g_Sk [(size_t)BB*NCH*128];
__device__ float g_Skp[(size_t)BB*NCH*128];

__device__ __forceinline__ float phi_f(float x){ return x > 0.f ? x + 1.f : __expf(x); }
__device__ __forceinline__ float sigm_f(float x){ return 1.f/(1.f+__expf(-x)); }

// Build tokens: [xs, ys] rows + [query_x, 0] final row.
__global__ __launch_bounds__(256) void k0_build(const float* __restrict__ xs,
                                                const float* __restrict__ ys,
                                                const float* __restrict__ qx){
  long e = (long)blockIdx.x * 256 + threadIdx.x;
  int col = (int)(e & 127);
  long r = e >> 7;
  int t = (int)(r & (TT-1));
  int b = (int)(r >> 12);
  float v;
  if (t < TT-1) {
    v = (col < 127) ? xs[((long)b*(TT-1) + t)*127 + col] : ys[(long)b*(TT-1) + t];
  } else {
    v = (col < 127) ? qx[(long)b*127 + col] : 0.f;
  }
  g_tok[e] = v;
}

// LN1 + projection GEMM, fused. 128 rows x 128 cols per block, k=128.
// grid = 64 tiles * 4 mats; mat 0=Q(phi) 1=K(phi) 2=V(raw->Pv) 3=G(raw->Pg).
// x staged row-major with LN applied in-register; W^T staged lane-diagonal.
// Compute tiling: thread (g=tid>>4, c=tid&15): rows {g+16i}, cols {c*4, 64+c*4}.
__global__ __launch_bounds__(256) void k1b_gemm(
    const float* __restrict__ Wq, const float* __restrict__ Wk,
    const float* __restrict__ Wv, const float* __restrict__ Wg,
    const float* __restrict__ lnw, const float* __restrict__ lnb)
{
  __shared__ float xl[128*132];   // LN(x) row-major
  __shared__ float wt[128*132];   // W^T [k][j]
  int tid = threadIdx.x;
  int mat = blockIdx.x & 3;
  long row0 = (long)(blockIdx.x >> 2) * 128;
  const float* W = (mat==0) ? Wq : (mat==1) ? Wk : (mat==2) ? Wv : Wg;
  bool isQK = (mat < 2);
  // W^T stage (lane-diagonal, conflict-free writes)
  for (int i=0;i<16;i++){
    int ts = (tid & 31) + 32*(i & 3);     // output col j
    int hc = (tid >> 5) + 8*(i >> 2);     // k group of 4
    int wr = isQK ? (ts < 127 ? ts : 126) : ts;
    float4 v = *(const float4*)(W + (long)wr*128 + hc*4);
    wt[(hc*4+0)*132+ts] = v.x;
    wt[(hc*4+1)*132+ts] = v.y;
    wt[(hc*4+2)*132+ts] = v.z;
    wt[(hc*4+3)*132+ts] = v.w;
  }
  // x stage with fused LN: thread = (row=tid>>1, half=tid&1), 64 cols each
  {
    int row = tid >> 1, half = tid & 1;
    const float* src = g_tok + (row0 + row)*128 + half*64;
    float s1 = 0.f, s2 = 0.f;
    for (int u=0; u<16; u++){
      float4 v = *(const float4*)(src + u*4);
      s1 += v.x+v.y+v.z+v.w;
      s2 += v.x*v.x+v.y*v.y+v.z*v.z+v.w*v.w;
      *(float4*)&xl[row*132 + half*64 + u*4] = v;
    }
    s1 += __shfl_xor(s1, 1); s2 += __shfl_xor(s2, 1);
    float mean = s1*(1.f/128.f);
    float var  = s2*(1.f/128.f) - mean*mean;
    float rstd = rsqrtf(var + 1e-5f);
    for (int u=0; u<16; u++){
      int cc = half*64 + u*4;
      float4 v  = *(float4*)&xl[row*132 + cc];
      float4 w4 = *(const float4*)(lnw + cc);
      float4 b4 = *(const float4*)(lnb + cc);
      v.x = (v.x-mean)*rstd*w4.x + b4.x;
      v.y = (v.y-mean)*rstd*w4.y + b4.y;
      v.z = (v.z-mean)*rstd*w4.z + b4.z;
      v.w = (v.w-mean)*rstd*w4.w + b4.w;
      *(float4*)&xl[row*132 + cc] = v;
    }
  }
  __syncthreads();
  int g = tid >> 4, c = tid & 15;
  float acc[8][8];
  #pragma unroll
  for (int i=0;i<8;i++)
    #pragma unroll
    for (int j=0;j<8;j++) acc[i][j]=0.f;
  for (int k=0;k<128;k++){
    float xr[8];
    #pragma unroll
    for (int i=0;i<8;i++) xr[i] = xl[(g+16*i)*132 + k];
    float4 wa = *(const float4*)&wt[k*132 + c*4];
    float4 wb = *(const float4*)&wt[k*132 + 64 + c*4];
    float wc[8] = {wa.x,wa.y,wa.z,wa.w,wb.x,wb.y,wb.z,wb.w};
    #pragma unroll
    for (int i=0;i<8;i++)
      #pragma unroll
      for (int j=0;j<8;j++)
        acc[i][j] += xr[i]*wc[j];
  }
  if (isQK){
    float* dst = (mat==0) ? g_Qp : g_Kp;
    #pragma unroll
    for (int i=0;i<8;i++){
      long rr = row0 + g + 16*i;
      float v0[4], v1[4];
      #pragma unroll
      for (int j=0;j<4;j++) v0[j] = phi_f(acc[i][j]);          // cols <= 63
      #pragma unroll
      for (int j=0;j<4;j++){
        int col = 64 + c*4 + j;
        v1[j] = (col < 127) ? phi_f(acc[i][4+j]) : 0.f;
      }
      *(float4*)(dst + rr*128 + c*4)      = make_float4(v0[0],v0[1],v0[2],v0[3]);
      *(float4*)(dst + rr*128 + 64 + c*4) = make_float4(v1[0],v1[1],v1[2],v1[3]);
    }
  } else {
    float* dst = (mat==2) ? g_Pv : g_Pg;
    #pragma unroll
    for (int i=0;i<8;i++){
      long rr = row0 + g + 16*i;
      *(float4*)(dst + rr*128 + c*4)      = make_float4(acc[i][0],acc[i][1],acc[i][2],acc[i][3]);
      *(float4*)(dst + rr*128 + 64 + c*4) = make_float4(acc[i][4],acc[i][5],acc[i][6],acc[i][7]);
    }
  }
}

// Vg = Pv * sigmoid(Pg + b), vectorized.
__global__ __launch_bounds__(256) void k1c_vg(const float* __restrict__ Wgb){
  long e = ((long)blockIdx.x*256 + threadIdx.x) * 4;
  int j = (int)(e & 127);
  float4 pv = *(const float4*)(g_Pv + e);
  float4 pg = *(const float4*)(g_Pg + e);
  float4 gb = *(const float4*)(Wgb + j);
  float4 o;
  o.x = pv.x * sigm_f(pg.x + gb.x);
  o.y = pv.y * sigm_f(pg.y + gb.y);
  o.z = pv.z * sigm_f(pg.z + gb.z);
  o.w = pv.w * sigm_f(pg.w + gb.w);
  *(float4*)(g_Vg + e) = o;
}

// Per-chunk state sums: Ssum[b][c][h][m] = sum_t Kp*Vg ; Sk[b][c][h] = sum_t Kp.
__global__ __launch_bounds__(256) void k2_chunksum()
{
  __shared__ float vgs[16][128];
  __shared__ float kps[16][32];
  int tid = threadIdx.x;
  int ht = blockIdx.x & 3;
  int c  = (blockIdx.x >> 2) & 31;
  int b  = blockIdx.x >> 7;
  int hl = tid >> 3, mg = tid & 7, m0 = mg << 4;
  int h  = ht*32 + hl;
  float acc[16];
  #pragma unroll
  for (int i=0;i<16;i++) acc[i]=0.f;
  float sk = 0.f;
  long base = ((long)b*TT + c*128)*128;
  for (int tb=0; tb<8; tb++){
    __syncthreads();
    { int e = tid*8; int ts = e >> 7; int cc = e & 127;
      const float* s = g_Vg + base + (long)(tb*16+ts)*128 + cc;
      *(float4*)&vgs[ts][cc]   = *(const float4*)s;
      *(float4*)&vgs[ts][cc+4] = *(const float4*)(s+4); }
    { int e = tid*2; int ts = e >> 5; int hh = e & 31;
      const float* s = g_Kp + base + (long)(tb*16+ts)*128 + ht*32 + hh;
      kps[ts][hh] = s[0]; kps[ts][hh+1] = s[1]; }
    __syncthreads();
    for (int ts=0; ts<16; ts++){
      float kp = kps[ts][hl];
      sk += kp;
      #pragma unroll
      for (int i=0;i<16;i++) acc[i] += kp * vgs[ts][m0+i];
    }
  }
  long so = (((long)b*NCH + c)*128 + h)*128 + m0;
  #pragma unroll
  for (int i=0;i<16;i+=4)
    *(float4*)(g_Ssum + so + i) = make_float4(acc[i],acc[i+1],acc[i+2],acc[i+3]);
  if (mg==0) g_Sk[((long)b*NCH + c)*128 + h] = sk;
}

// Exclusive prefix scan over chunks for Ssum and Sk.
__global__ __launch_bounds__(256) void k3_scan()
{
  int blk = blockIdx.x % 65;
  int b   = blockIdx.x / 65;
  if (blk < 64){
    int e = blk*256 + threadIdx.x;
    float a = 0.f;
    for (int c=0;c<NCH;c++){
      long idx = ((long)b*NCH + c)*16384 + e;
      g_Spre[idx] = a;
      a += g_Ssum[idx];
    }
  } else if (threadIdx.x < 128){
    int e = threadIdx.x;
    float a = 0.f;
    for (int c=0;c<NCH;c++){
      long idx = ((long)b*NCH + c)*128 + e;
      g_Skp[idx] = a;
      a += g_Sk[idx];
    }
  }
}

// Fused inter+intra attention + Wo + residual + LN2, in place on g_tok.
// Grid: BB*NCH*4 = 256 blocks; block owns 32 rows of one chunk.
// Thread tiling: rp=tid>>4 (rows 2rp,2rp+1), cg=tid&15 (cols cg*4 & 64+cg*4).
__global__ __launch_bounds__(256) void k4_fused(
    const float* __restrict__ Wo,
    const float* __restrict__ ln2w, const float* __restrict__ ln2b)
{
  __shared__ float spl[128*132];   // Spre padded [h*132+n]           (67.6 KB)
  __shared__ float ktl[128*132];   // K^T [h][ts] -> Vg flat -> Wo^T  (67.6 KB)
  __shared__ float bufb[32*132];   // Qp rows -> A rows -> attn rows  (16.9 KB)
  __shared__ float skl[128];
  int tid = threadIdx.x;
  int rq = blockIdx.x & 3;
  int c  = (blockIdx.x >> 2) & 31;
  int b  = blockIdx.x >> 7;
  int r0 = rq*32;
  long cbase = ((long)b*TT + c*128)*128;
  long sbase = ((long)b*NCH + c)*16384;

  for (int i=0;i<16;i++){
    int e = i*1024 + tid*4;
    int h = e >> 7, n = e & 127;
    *(float4*)&spl[h*132+n] = *(const float4*)(g_Spre + sbase + e);
  }
  if (tid < 128) skl[tid] = g_Skp[((long)b*NCH + c)*128 + tid];
  for (int i=0;i<4;i++){
    int e = i*1024 + tid*4;
    int row = e >> 7, cc = e & 127;
    *(float4*)&bufb[row*132+cc] = *(const float4*)(g_Qp + cbase + (long)(r0+row)*128 + cc);
  }
  for (int i=0;i<16;i++){
    int ts = (tid & 31) + 32*(i & 3);
    int hc = (tid >> 5) + 8*(i >> 2);
    float4 v = *(const float4*)(g_Kp + cbase + (long)ts*128 + hc*4);
    ktl[(hc*4+0)*132 + ts] = v.x;
    ktl[(hc*4+1)*132 + ts] = v.y;
    ktl[(hc*4+2)*132 + ts] = v.z;
    ktl[(hc*4+3)*132 + ts] = v.w;
  }
  __syncthreads();

  int rp = tid >> 4, cg = tid & 15;
  int rl0 = rp*2, rl1 = rp*2+1;
  int tq0 = r0 + rl0, tq1 = r0 + rl1;
  float acc2[2][8], a[2][8];
  #pragma unroll
  for (int r=0;r<2;r++)
    #pragma unroll
    for (int j=0;j<8;j++){ acc2[r][j]=0.f; a[r][j]=0.f; }
  float den0 = 0.f, den1 = 0.f;
  for (int h=0;h<128;h++){
    float q0 = bufb[rl0*132 + h];
    float q1 = bufb[rl1*132 + h];
    float sv = skl[h];
    den0 += q0*sv; den1 += q1*sv;
    float4 sa = *(const float4*)&spl[h*132 + cg*4];
    float4 sb = *(const float4*)&spl[h*132 + 64 + cg*4];
    float4 ka = *(const float4*)&ktl[h*132 + cg*4];
    float4 kb = *(const float4*)&ktl[h*132 + 64 + cg*4];
    acc2[0][0]+=q0*sa.x; acc2[0][1]+=q0*sa.y; acc2[0][2]+=q0*sa.z; acc2[0][3]+=q0*sa.w;
    acc2[0][4]+=q0*sb.x; acc2[0][5]+=q0*sb.y; acc2[0][6]+=q0*sb.z; acc2[0][7]+=q0*sb.w;
    acc2[1][0]+=q1*sa.x; acc2[1][1]+=q1*sa.y; acc2[1][2]+=q1*sa.z; acc2[1][3]+=q1*sa.w;
    acc2[1][4]+=q1*sb.x; acc2[1][5]+=q1*sb.y; acc2[1][6]+=q1*sb.z; acc2[1][7]+=q1*sb.w;
    a[0][0]+=q0*ka.x; a[0][1]+=q0*ka.y; a[0][2]+=q0*ka.z; a[0][3]+=q0*ka.w;
    a[0][4]+=q0*kb.x; a[0][5]+=q0*kb.y; a[0][6]+=q0*kb.z; a[0][7]+=q0*kb.w;
    a[1][0]+=q1*ka.x; a[1][1]+=q1*ka.y; a[1][2]+=q1*ka.z; a[1][3]+=q1*ka.w;
    a[1][4]+=q1*kb.x; a[1][5]+=q1*kb.y; a[1][6]+=q1*kb.z; a[1][7]+=q1*kb.w;
  }
  float dena0 = 0.f, dena1 = 0.f;
  #pragma unroll
  for (int j=0;j<8;j++){
    int ts = (j<4) ? (cg*4+j) : (64 + cg*4 + j-4);
    if (ts > tq0) a[0][j] = 0.f;
    if (ts > tq1) a[1][j] = 0.f;
    dena0 += a[0][j]; dena1 += a[1][j];
  }
  dena0 += __shfl_xor(dena0,1); dena1 += __shfl_xor(dena1,1);
  dena0 += __shfl_xor(dena0,2); dena1 += __shfl_xor(dena1,2);
  dena0 += __shfl_xor(dena0,4); dena1 += __shfl_xor(dena1,4);
  dena0 += __shfl_xor(dena0,8); dena1 += __shfl_xor(dena1,8);
  float inv0 = 1.f / fmaxf(den0 + dena0, 1e-6f);
  float inv1 = 1.f / fmaxf(den1 + dena1, 1e-6f);
  __syncthreads();
  // A -> bufb ; Vg -> ktl flat [ts*128+n]
  *(float4*)&bufb[rl0*132 + cg*4]      = make_float4(a[0][0],a[0][1],a[0][2],a[0][3]);
  *(float4*)&bufb[rl0*132 + 64 + cg*4] = make_float4(a[0][4],a[0][5],a[0][6],a[0][7]);
  *(float4*)&bufb[rl1*132 + cg*4]      = make_float4(a[1][0],a[1][1],a[1][2],a[1][3]);
  *(float4*)&bufb[rl1*132 + 64 + cg*4] = make_float4(a[1][4],a[1][5],a[1][6],a[1][7]);
  for (int i=0;i<16;i++){
    int e = i*1024 + tid*4;
    *(float4*)&ktl[e] = *(const float4*)(g_Vg + cbase + e);
  }
  __syncthreads();
  for (int ts=0; ts<128; ts++){
    float a0 = bufb[rl0*132 + ts];
    float a1 = bufb[rl1*132 + ts];
    float4 va = *(const float4*)&ktl[ts*128 + cg*4];
    float4 vb = *(const float4*)&ktl[ts*128 + 64 + cg*4];
    acc2[0][0]+=a0*va.x; acc2[0][1]+=a0*va.y; acc2[0][2]+=a0*va.z; acc2[0][3]+=a0*va.w;
    acc2[0][4]+=a0*vb.x; acc2[0][5]+=a0*vb.y; acc2[0][6]+=a0*vb.z; acc2[0][7]+=a0*vb.w;
    acc2[1][0]+=a1*va.x; acc2[1][1]+=a1*va.y; acc2[1][2]+=a1*va.z; acc2[1][3]+=a1*va.w;
    acc2[1][4]+=a1*vb.x; acc2[1][5]+=a1*vb.y; acc2[1][6]+=a1*vb.z; acc2[1][7]+=a1*vb.w;
  }
  __syncthreads();
  // attn -> bufb ; Wo^T -> ktl [m][n] padded (lane-diagonal)
  *(float4*)&bufb[rl0*132 + cg*4]      = make_float4(acc2[0][0]*inv0,acc2[0][1]*inv0,acc2[0][2]*inv0,acc2[0][3]*inv0);
  *(float4*)&bufb[rl0*132 + 64 + cg*4] = make_float4(acc2[0][4]*inv0,acc2[0][5]*inv0,acc2[0][6]*inv0,acc2[0][7]*inv0);
  *(float4*)&bufb[rl1*132 + cg*4]      = make_float4(acc2[1][0]*inv1,acc2[1][1]*inv1,acc2[1][2]*inv1,acc2[1][3]*inv1);
  *(float4*)&bufb[rl1*132 + 64 + cg*4] = make_float4(acc2[1][4]*inv1,acc2[1][5]*inv1,acc2[1][6]*inv1,acc2[1][7]*inv1);
  for (int i=0;i<16;i++){
    int n  = (tid & 31) + 32*(i & 3);
    int mc = (tid >> 5) + 8*(i >> 2);
    float4 v = *(const float4*)(Wo + (long)n*128 + mc*4);
    ktl[(mc*4+0)*132 + n] = v.x;
    ktl[(mc*4+1)*132 + n] = v.y;
    ktl[(mc*4+2)*132 + n] = v.z;
    ktl[(mc*4+3)*132 + n] = v.w;
  }
  __syncthreads();
  float s[2][8];
  #pragma unroll
  for (int r=0;r<2;r++)
    #pragma unroll
    for (int j=0;j<8;j++) s[r][j]=0.f;
  for (int m=0;m<128;m++){
    float a0 = bufb[rl0*132 + m];
    float a1 = bufb[rl1*132 + m];
    float4 wa = *(const float4*)&ktl[m*132 + cg*4];
    float4 wb = *(const float4*)&ktl[m*132 + 64 + cg*4];
    s[0][0]+=a0*wa.x; s[0][1]+=a0*wa.y; s[0][2]+=a0*wa.z; s[0][3]+=a0*wa.w;
    s[0][4]+=a0*wb.x; s[0][5]+=a0*wb.y; s[0][6]+=a0*wb.z; s[0][7]+=a0*wb.w;
    s[1][0]+=a1*wa.x; s[1][1]+=a1*wa.y; s[1][2]+=a1*wa.z; s[1][3]+=a1*wa.w;
    s[1][4]+=a1*wb.x; s[1][5]+=a1*wb.y; s[1][6]+=a1*wb.z; s[1][7]+=a1*wb.w;
  }
  long trow0 = (long)b*TT + c*128 + tq0;
  long trow1 = (long)b*TT + c*128 + tq1;
  float outv[2][8];
  {
    float4 t0a = *(const float4*)(g_tok + trow0*128 + cg*4);
    float4 t0b = *(const float4*)(g_tok + trow0*128 + 64 + cg*4);
    float4 t1a = *(const float4*)(g_tok + trow1*128 + cg*4);
    float4 t1b = *(const float4*)(g_tok + trow1*128 + 64 + cg*4);
    outv[0][0]=t0a.x+0.1f*s[0][0]; outv[0][1]=t0a.y+0.1f*s[0][1];
    outv[0][2]=t0a.z+0.1f*s[0][2]; outv[0][3]=t0a.w+0.1f*s[0][3];
    outv[0][4]=t0b.x+0.1f*s[0][4]; outv[0][5]=t0b.y+0.1f*s[0][5];
    outv[0][6]=t0b.z+0.1f*s[0][6]; outv[0][7]=t0b.w+0.1f*s[0][7];
    outv[1][0]=t1a.x+0.1f*s[1][0]; outv[1][1]=t1a.y+0.1f*s[1][1];
    outv[1][2]=t1a.z+0.1f*s[1][2]; outv[1][3]=t1a.w+0.1f*s[1][3];
    outv[1][4]=t1b.x+0.1f*s[1][4]; outv[1][5]=t1b.y+0.1f*s[1][5];
    outv[1][6]=t1b.z+0.1f*s[1][6]; outv[1][7]=t1b.w+0.1f*s[1][7];
  }
  float s10=0.f, s20=0.f, s11=0.f, s21=0.f;
  #pragma unroll
  for (int j=0;j<8;j++){
    s10 += outv[0][j]; s20 += outv[0][j]*outv[0][j];
    s11 += outv[1][j]; s21 += outv[1][j]*outv[1][j];
  }
  s10 += __shfl_xor(s10,1); s20 += __shfl_xor(s20,1); s11 += __shfl_xor(s11,1); s21 += __shfl_xor(s21,1);
  s10 += __shfl_xor(s10,2); s20 += __shfl_xor(s20,2); s11 += __shfl_xor(s11,2); s21 += __shfl_xor(s21,2);
  s10 += __shfl_xor(s10,4); s20 += __shfl_xor(s20,4); s11 += __shfl_xor(s11,4); s21 += __shfl_xor(s21,4);
  s10 += __shfl_xor(s10,8); s20 += __shfl_xor(s20,8); s11 += __shfl_xor(s11,8); s21 += __shfl_xor(s21,8);
  float mean0 = s10*(1.f/128.f), var0 = s20*(1.f/128.f)-mean0*mean0, rstd0 = rsqrtf(var0+1e-5f);
  float mean1 = s11*(1.f/128.f), var1 = s21*(1.f/128.f)-mean1*mean1, rstd1 = rsqrtf(var1+1e-5f);
  #pragma unroll
  for (int half=0; half<2; half++){
    int n = half*64 + cg*4;
    float4 w4 = *(const float4*)(ln2w+n);
    float4 b4 = *(const float4*)(ln2b+n);
    float4 o0, o1;
    o0.x=(outv[0][half*4+0]-mean0)*rstd0*w4.x+b4.x;
    o0.y=(outv[0][half*4+1]-mean0)*rstd0*w4.y+b4.y;
    o0.z=(outv[0][half*4+2]-mean0)*rstd0*w4.z+b4.z;
    o0.w=(outv[0][half*4+3]-mean0)*rstd0*w4.w+b4.w;
    o1.x=(outv[1][half*4+0]-mean1)*rstd1*w4.x+b4.x;
    o1.y=(outv[1][half*4+1]-mean1)*rstd1*w4.y+b4.y;
    o1.z=(outv[1][half*4+2]-mean1)*rstd1*w4.z+b4.z;
    o1.w=(outv[1][half*4+3]-mean1)*rstd1*w4.w+b4.w;
    *(float4*)(g_tok + trow0*128 + n) = o0;
    *(float4*)(g_tok + trow1*128 + n) = o1;
  }
}

__global__ __launch_bounds__(128) void k5_pred(const float* __restrict__ pw,
                                               float* __restrict__ out){
  __shared__ float red[2];
  int b = blockIdx.x, tid = threadIdx.x;
  float v = g_tok[((long)b*TT + TT-1)*128 + tid] * pw[tid];
  #pragma unroll
  for (int off=1; off<64; off<<=1) v += __shfl_xor(v, off);
  if ((tid & 63) == 0) red[tid>>6] = v;
  __syncthreads();
  if (tid==0) out[b] = red[0] + red[1];
}

extern "C" void kernel_launch(void* const* d_in, const int* in_sizes, int n_in,
                              void* d_out, int out_size, void* d_ws, size_t ws_size,
                              hipStream_t stream)
{
  (void)in_sizes; (void)n_in; (void)out_size; (void)d_ws; (void)ws_size;
  const float* xs   = (const float*)d_in[0];
  const float* ys   = (const float*)d_in[1];
  const float* qx   = (const float*)d_in[2];
  const float* Wq   = (const float*)d_in[3];
  const float* Wk   = (const float*)d_in[4];
  const float* Wv   = (const float*)d_in[5];
  const float* Wgw  = (const float*)d_in[6];
  const float* Wgb  = (const float*)d_in[7];
  const float* Wo   = (const float*)d_in[8];
  const float* ln1w = (const float*)d_in[9];
  const float* ln1b = (const float*)d_in[10];
  const float* ln2w = (const float*)d_in[11];
  const float* ln2b = (const float*)d_in[12];
  const float* predw= (const float*)d_in[13];

  k0_build<<<4096, 256, 0, stream>>>(xs, ys, qx);

  for (int l=0; l<2; l++){
    const float* Wq_l  = Wq  + (size_t)l*127*128;
    const float* Wk_l  = Wk  + (size_t)l*127*128;
    const float* Wv_l  = Wv  + (size_t)l*128*128;
    const float* Wgw_l = Wgw + (size_t)l*128*128;
    const float* Wgb_l = Wgb + (size_t)l*128;
    const float* Wo_l  = Wo  + (size_t)l*128*128;
    const float* l1w = ln1w + (size_t)l*128;
    const float* l1b = ln1b + (size_t)l*128;
    const float* l2w = ln2w + (size_t)l*128;
    const float* l2b = ln2b + (size_t)l*128;

    k1b_gemm<<<256, 256, 0, stream>>>(Wq_l, Wk_l, Wv_l, Wgw_l, l1w, l1b);
    k1c_vg<<<1024, 256, 0, stream>>>(Wgb_l);
    k2_chunksum<<<256, 256, 0, stream>>>();
    k3_scan<<<130, 256, 0, stream>>>();
    k4_fused<<<256, 256, 0, stream>>>(Wo_l, l2w, l2b);
  }
  k5_pred<<<BB, 128, 0, stream>>>(predw, (float*)d_out);
}